// Round 8
// baseline (84.989 us; speedup 1.0000x reference)
//
#include <hip/hip_runtime.h>

#define QLEN 1024
#define KLEN 1024
#define BSZ 2
#define NHEAD 16
#define DHEAD 64
#define RS 2048            /* BSZ*NHEAD*DHEAD floats per seq row */
#define BLK_I 64
#define BLK_J 64
#define NJT_FULL (KLEN / BLK_J)
#define NBN (BSZ * NHEAD)

#define SC2f  0.18033688011112440f   /* 0.125 * log2(e) */
#define MBIGf 1.4426950408889634e30f /* 1e30 * log2(e)  */

#define SEGP_BYTES  16777216u                     /* BSZ*QLEN*KLEN*8  */
#define KT_BYTES    ((size_t)NBN * NJT_FULL * 8192) /* 4 MiB per tensor */
#define OPART_BYTES 16777216u                     /* 2*NBN*QLEN*64*4  */
#define ML_BYTES    524288u                       /* 2*NBN*QLEN*2*4   */

typedef __attribute__((ext_vector_type(8))) short s16x8;
typedef __attribute__((ext_vector_type(8))) unsigned short u16x8;
typedef __attribute__((ext_vector_type(4))) unsigned short u16x4;
typedef __attribute__((ext_vector_type(4))) float f32x4;
typedef __attribute__((ext_vector_type(2))) float f32x2;

__device__ __forceinline__ unsigned short f2bf(float f) {
    union { float f; unsigned int u; } x; x.f = f;
    unsigned int r = x.u + 0x7fffu + ((x.u >> 16) & 1u);
    return (unsigned short)(r >> 16);
}
__device__ __forceinline__ float bf2f(unsigned short h) {
    union { unsigned int u; float f; } x; x.u = ((unsigned int)h) << 16;
    return x.f;
}

typedef const __attribute__((address_space(1))) unsigned int* gas_t;
typedef __attribute__((address_space(3))) unsigned int* las_t;
__device__ __forceinline__ void gl_lds16(const void* g, void* l) {
    __builtin_amdgcn_global_load_lds((gas_t)g, (las_t)l, 16, 0, 0);
}

// ---- pre-pass 1: pack segmat+mask -> [b][i][j] {bf16 s0, s1, mk*MBIG, 0} ----
__global__ __launch_bounds__(256)
void pack_seg_kernel(const float* __restrict__ segmat,
                     const float* __restrict__ mask,
                     u16x4* __restrict__ segP)
{
    const int gid = blockIdx.x * 256 + threadIdx.x;   // BSZ*QLEN*KLEN/8 items
    const int j8  = gid & (KLEN / 8 - 1);
    const int i   = (gid >> 7) & (QLEN - 1);
    const int b   = gid >> 17;
    const float* sp = segmat + ((size_t)(i * KLEN + j8 * 8) * BSZ + b) * 2;
    const float* mp = mask + (size_t)i * KLEN + j8 * 8;
    u16x4* op = segP + (size_t)(b * QLEN + i) * KLEN + j8 * 8;
#pragma unroll
    for (int e = 0; e < 8; ++e) {
        const f32x2 sm = *(const f32x2*)(sp + e * (BSZ * 2));
        u16x4 pk;
        pk[0] = f2bf(sm[0]); pk[1] = f2bf(sm[1]);
        pk[2] = f2bf(mp[e] * MBIGf); pk[3] = 0;
        op[e] = pk;
    }
}

// ---- pre-pass 2: pack Kh, Kr(+1), V^T as flat 8KB bf16 tiles, swizzled ------
__global__ __launch_bounds__(256)
void pack_kv_kernel(const float* __restrict__ kh,
                    const float* __restrict__ kr,
                    const float* __restrict__ v,
                    unsigned short* __restrict__ Kp,
                    unsigned short* __restrict__ Krp,
                    unsigned short* __restrict__ Vtp)
{
    __shared__ float VT[64][65];
    const int blk = blockIdx.x;           // bn*NJT_FULL + jt
    const int bn  = blk >> 4;
    const int jt  = blk & (NJT_FULL - 1);
    const int b   = bn & 1;
    const int n   = bn >> 1;
    const int boff = b * NHEAD * DHEAD + n * DHEAD;
    const int j0  = jt * BLK_J;
    const int tid = threadIdx.x;

    {   // v tile -> LDS (coalesced)
        const int j  = tid >> 2;
        const int dq = (tid & 3) * 16;
        const float* vp = v + (size_t)(j0 + j) * RS + boff + dq;
#pragma unroll
        for (int e = 0; e < 16; ++e) VT[j][dq + e] = vp[e];
    }
    __syncthreads();

    const size_t tb = (size_t)blk * 4096;   // u16 units (8KB tiles)
#pragma unroll
    for (int h = 0; h < 2; ++h) {
        const int p   = tid + h * 256;      // 16B chunk id 0..511
        const int row = p >> 3;
        const int ch  = (p & 7) ^ (row & 7);
        u16x8 ok, orr, ov;
        const float* hp = kh + (size_t)(j0 + row) * RS + boff + ch * 8;
        const float* rp = kr + (size_t)(j0 + row + 1) * RS + boff + ch * 8; // shift +1
#pragma unroll
        for (int e = 0; e < 8; ++e) {
            ok[e]  = f2bf(hp[e]);
            orr[e] = f2bf(rp[e]);
            ov[e]  = f2bf(VT[ch * 8 + e][row]);
        }
        *(u16x8*)&Kp [tb + (size_t)p * 8] = ok;
        *(u16x8*)&Krp[tb + (size_t)p * 8] = orr;
        *(u16x8*)&Vtp[tb + (size_t)p * 8] = ov;
    }
}

// ---- merge: combine 2 j-half partials ---------------------------------------
__global__ __launch_bounds__(256)
void merge_kernel(const float* __restrict__ opart,
                  const float* __restrict__ ml,
                  float* __restrict__ out)
{
    const int gid = blockIdx.x * 256 + threadIdx.x;   // NBN*QLEN*64 items
    const int d   = gid & 63;
    const int rr  = gid >> 6;                          // (b*NHEAD+n)*QLEN + i
    const int i   = rr & (QLEN - 1);
    const int n   = (rr >> 10) & (NHEAD - 1);
    const int b   = rr >> 14;
    const int r0  = rr;
    const int r1  = (NBN * QLEN) + rr;
    const float m0 = ml[r0 * 2], l0 = ml[r0 * 2 + 1];
    const float m1 = ml[r1 * 2], l1 = ml[r1 * 2 + 1];
    const float M  = fmaxf(m0, m1);
    const float w0 = __builtin_amdgcn_exp2f(m0 - M);
    const float w1 = __builtin_amdgcn_exp2f(m1 - M);
    const float inv = 1.f / (l0 * w0 + l1 * w1);
    const float o = (opart[(size_t)r0 * 64 + d] * w0 + opart[(size_t)r1 * 64 + d] * w1) * inv;
    out[(size_t)i * RS + b * NHEAD * DHEAD + n * DHEAD + d] = o;
}

// ---- main: swapped-QK (S^T in regs, lane-local softmax rows) -----------------
__global__ __launch_bounds__(256, 3)
void relattn_kernel(const float* __restrict__ q,
                    const float* __restrict__ segemb,
                    const float* __restrict__ rwb,
                    const float* __restrict__ rrb,
                    const float* __restrict__ rsb,
                    const u16x4* __restrict__ segP,
                    const unsigned short* __restrict__ Kp,
                    const unsigned short* __restrict__ Krp,
                    const unsigned short* __restrict__ Vtp,
                    float* __restrict__ opart,
                    float* __restrict__ mlpart,
                    float* __restrict__ out,
                    int jsplit, int njt)
{
    __shared__ unsigned short KhL[2][64][64];
    __shared__ unsigned short KrL[2][64][64];
    __shared__ unsigned short VtL[2][64][64];
    __shared__ unsigned short PlP[4][16][40];   // per-wave P^T xchg buffer (5KB)

    const int i0  = blockIdx.x * BLK_I;
    const int jsp = blockIdx.y;
    const int bn  = blockIdx.z;
    const int b   = bn & 1;
    const int n   = bn >> 1;
    const int boff = b * NHEAD * DHEAD + n * DHEAD;

    const int tid  = threadIdx.x;
    const int wave = tid >> 6;
    const int lane = tid & 63;
    const int q4   = lane >> 4;
    const int c    = lane & 15;
    const int ih   = wave >> 1;   // i-half: rows ih*32..+32
    const int jh   = wave & 1;    // j-half: cols jh*32..+32

    // ---- Q fragments + in-lane ef0 (fused with Q f32 loads; no LDS) ----
    s16x8 qwf[2][2], qrf[2][2];
    float e0[2], e1[2];
#pragma unroll
    for (int isub = 0; isub < 2; ++isub) {
        const float* qp = q + (size_t)(i0 + ih * 32 + isub * 16 + c) * RS + boff;
        float es0 = 0.f, es1 = 0.f;
#pragma unroll
        for (int kk = 0; kk < 2; ++kk) {
            const int off = kk * 32 + q4 * 8;
            const f32x4 q0 = *(const f32x4*)(qp + off);
            const f32x4 q1 = *(const f32x4*)(qp + off + 4);
            const f32x4 w0 = *(const f32x4*)(rwb + n * DHEAD + off);
            const f32x4 w1 = *(const f32x4*)(rwb + n * DHEAD + off + 4);
            const f32x4 r0 = *(const f32x4*)(rrb + n * DHEAD + off);
            const f32x4 r1 = *(const f32x4*)(rrb + n * DHEAD + off + 4);
            const f32x4 sa = *(const f32x4*)(segemb + n * DHEAD + off);
            const f32x4 sb = *(const f32x4*)(segemb + n * DHEAD + off + 4);
            const f32x4 ta = *(const f32x4*)(segemb + (NHEAD + n) * DHEAD + off);
            const f32x4 tb = *(const f32x4*)(segemb + (NHEAD + n) * DHEAD + off + 4);
            const f32x4 ra = *(const f32x4*)(rsb + n * DHEAD + off);
            const f32x4 rb = *(const f32x4*)(rsb + n * DHEAD + off + 4);
            s16x8 tw, tr;
#pragma unroll
            for (int e = 0; e < 4; ++e) {
                tw[e]     = (short)f2bf(q0[e] + w0[e]);
                tw[4 + e] = (short)f2bf(q1[e] + w1[e]);
                tr[e]     = (short)f2bf(q0[e] + r0[e]);
                tr[4 + e] = (short)f2bf(q1[e] + r1[e]);
                es0 += (q0[e] + ra[e]) * sa[e] + (q1[e] + rb[e]) * sb[e];
                es1 += (q0[e] + ra[e]) * ta[e] + (q1[e] + rb[e]) * tb[e];
            }
            qwf[isub][kk] = tw; qrf[isub][kk] = tr;
        }
        es0 += __shfl_xor(es0, 16, 64); es0 += __shfl_xor(es0, 32, 64);
        es1 += __shfl_xor(es1, 16, 64); es1 += __shfl_xor(es1, 32, 64);
        e0[isub] = es0 * SC2f; e1[isub] = es1 * SC2f;
    }

    // ---- async DMA staging ----
    const int tbase = bn * NJT_FULL + jsp * njt;
    auto stage = [&](int jt, int buf) {
        const size_t toff = ((size_t)(tbase + jt)) << 13;
        const int go = wave * 1024 + lane * 16;
        const int lo = wave * 1024;
#pragma unroll
        for (int h = 0; h < 2; ++h) {
            gl_lds16((const char*)Kp  + toff + go + h * 4096, (char*)&KhL[buf][0][0] + lo + h * 4096);
            gl_lds16((const char*)Krp + toff + go + h * 4096, (char*)&KrL[buf][0][0] + lo + h * 4096);
            gl_lds16((const char*)Vtp + toff + go + h * 4096, (char*)&VtL[buf][0][0] + lo + h * 4096);
        }
    };

    stage(0, 0);
    __syncthreads();

    float mreg[2] = { -INFINITY, -INFINITY };
    float lsum[2] = { 0.f, 0.f };
    f32x4 acc[2][4];
#pragma unroll
    for (int isub = 0; isub < 2; ++isub)
#pragma unroll
        for (int dt = 0; dt < 4; ++dt) acc[isub][dt] = (f32x4)0.f;

    const u16x4* spB = segP + (size_t)b * QLEN * KLEN;
    int cur = 0;
    for (int jt = 0; jt < njt; ++jt) {
        if (jt + 1 < njt) stage(jt + 1, cur ^ 1);   // DMA flies under compute

        // ---- seg/mask gathers: lane-local rows (i=c), 2x16B per (isub,js) ----
        const int jb = (jsp * njt + jt) * BLK_J + jh * 32;
        u16x8 pg[2][2][2];
#pragma unroll
        for (int isub = 0; isub < 2; ++isub)
#pragma unroll
            for (int js = 0; js < 2; ++js) {
                const u16x4* pp = spB + (size_t)(i0 + ih * 32 + isub * 16 + c) * KLEN
                                  + jb + js * 16 + q4 * 4;
                pg[isub][js][0] = *(const u16x8*)pp;
                pg[isub][js][1] = *(const u16x8*)(pp + 2);
            }

        // ---- S^T = (Kh Qw^T + Kr Qr^T): D[j][i], lane holds row i=c ----
        f32x4 sjT[2][2];
#pragma unroll
        for (int isub = 0; isub < 2; ++isub) { sjT[isub][0] = (f32x4)0.f; sjT[isub][1] = (f32x4)0.f; }
        __builtin_amdgcn_s_setprio(1);
#pragma unroll
        for (int kk = 0; kk < 2; ++kk)
#pragma unroll
            for (int js = 0; js < 2; ++js) {
                const int row = jh * 32 + js * 16 + c;
                const int pcK = ((kk * 4 + q4) ^ (c & 7)) * 8;
                const s16x8 khf = *(const s16x8*)&KhL[cur][row][pcK];
                const s16x8 krf = *(const s16x8*)&KrL[cur][row][pcK];
#pragma unroll
                for (int isub = 0; isub < 2; ++isub) {
                    sjT[isub][js] = __builtin_amdgcn_mfma_f32_16x16x32_bf16(khf, qwf[isub][kk], sjT[isub][js], 0, 0, 0);
                    sjT[isub][js] = __builtin_amdgcn_mfma_f32_16x16x32_bf16(krf, qrf[isub][kk], sjT[isub][js], 0, 0, 0);
                }
            }
        __builtin_amdgcn_s_setprio(0);

        // ---- bias + lane-local online softmax + PV, per isub ----
#pragma unroll
        for (int isub = 0; isub < 2; ++isub) {
            float p[8];
#pragma unroll
            for (int js = 0; js < 2; ++js)
#pragma unroll
                for (int r = 0; r < 4; ++r) {
                    const u16x8 g = pg[isub][js][r >> 1];
                    const int bb = (r & 1) * 4;
                    const float bias = bf2f(g[bb]) * e0[isub] + bf2f(g[bb + 1]) * e1[isub]
                                       - bf2f(g[bb + 2]);
                    sjT[isub][js][r] = sjT[isub][js][r] * SC2f + bias;
                }
            float mt = fmaxf(
                fmaxf(fmaxf(sjT[isub][0][0], sjT[isub][0][1]), fmaxf(sjT[isub][0][2], sjT[isub][0][3])),
                fmaxf(fmaxf(sjT[isub][1][0], sjT[isub][1][1]), fmaxf(sjT[isub][1][2], sjT[isub][1][3])));
            mt = fmaxf(mt, __shfl_xor(mt, 16, 64));
            mt = fmaxf(mt, __shfl_xor(mt, 32, 64));
            const float mn  = fmaxf(mreg[isub], mt);
            const float scl = __builtin_amdgcn_exp2f(mreg[isub] - mn);
            mreg[isub] = mn;
#pragma unroll
            for (int dt = 0; dt < 4; ++dt) acc[isub][dt] *= scl;
            float ps = 0.f;
#pragma unroll
            for (int js = 0; js < 2; ++js)
#pragma unroll
                for (int r = 0; r < 4; ++r) {
                    const float pv = __builtin_amdgcn_exp2f(sjT[isub][js][r] - mn);
                    p[js * 4 + r] = pv;
                    ps += pv;
                }
            lsum[isub] = lsum[isub] * scl + ps;

            // pack P^T -> PlP (q4-crosslane redistribution via LDS)
#pragma unroll
            for (int js = 0; js < 2; ++js) {
                unsigned int wlo, whi;
                asm("v_cvt_pk_bf16_f32 %0, %1, %2" : "=v"(wlo) : "v"(p[js * 4 + 0]), "v"(p[js * 4 + 1]));
                asm("v_cvt_pk_bf16_f32 %0, %1, %2" : "=v"(whi) : "v"(p[js * 4 + 2]), "v"(p[js * 4 + 3]));
                uint2 wv; wv.x = wlo; wv.y = whi;
                *(uint2*)((char*)&PlP[wave][c][0] + js * 32 + q4 * 8) = wv;
            }
            const s16x8 pf = *(const s16x8*)&PlP[wave][c][q4 * 8];

            // PV: acc^T[d][i] += V^T(16d x 32j) * P^T(32j x 16i)
            __builtin_amdgcn_s_setprio(1);
#pragma unroll
            for (int dt = 0; dt < 4; ++dt) {
                const s16x8 vf = *(const s16x8*)&VtL[cur][dt * 16 + c]
                                   [((jh * 4 + q4) ^ (c & 7)) * 8];
                acc[isub][dt] = __builtin_amdgcn_mfma_f32_16x16x32_bf16(vf, pf, acc[isub][dt], 0, 0, 0);
            }
            __builtin_amdgcn_s_setprio(0);
        }

        __syncthreads();   // drains DMA + all waves done with buf[cur]
        cur ^= 1;
    }

    // ---- full-row lsum (reduce over q4 groups) ----
#pragma unroll
    for (int isub = 0; isub < 2; ++isub) {
        lsum[isub] += __shfl_xor(lsum[isub], 16, 64);
        lsum[isub] += __shfl_xor(lsum[isub], 32, 64);
    }

    // ---- jh merge via LDS, then store ----
    __syncthreads();
    float* scrO  = (float*)&KhL[0][0][0];   // [64][68] f32 (17.4KB over Kh+Kr)
    float* scrML = (float*)&VtL[0][0][0];   // [64][2]
    if (jh == 1) {
#pragma unroll
        for (int isub = 0; isub < 2; ++isub) {
            const int rowL = ih * 32 + isub * 16 + c;
#pragma unroll
            for (int dt = 0; dt < 4; ++dt)
                *(f32x4*)&scrO[rowL * 68 + dt * 16 + q4 * 4] = acc[isub][dt];
            if (q4 == 0) {
                scrML[rowL * 2]     = mreg[isub];
                scrML[rowL * 2 + 1] = lsum[isub];
            }
        }
    }
    __syncthreads();
    if (jh == 0) {
#pragma unroll
        for (int isub = 0; isub < 2; ++isub) {
            const int rowL = ih * 32 + isub * 16 + c;
            const float m1 = scrML[rowL * 2];
            const float l1 = scrML[rowL * 2 + 1];
            const float M  = fmaxf(mreg[isub], m1);
            const float w0 = __builtin_amdgcn_exp2f(mreg[isub] - M);
            const float w1 = __builtin_amdgcn_exp2f(m1 - M);
            const float L  = lsum[isub] * w0 + l1 * w1;
            if (jsplit) {
                const int rowG = ((jsp * BSZ + b) * NHEAD + n) * QLEN + i0 + rowL;
#pragma unroll
                for (int dt = 0; dt < 4; ++dt) {
                    const f32x4 o = acc[isub][dt] * w0
                                  + (*(const f32x4*)&scrO[rowL * 68 + dt * 16 + q4 * 4]) * w1;
                    *(f32x4*)&opart[(size_t)rowG * 64 + dt * 16 + q4 * 4] = o;
                }
                if (q4 == 0) {
                    mlpart[(size_t)rowG * 2]     = M;
                    mlpart[(size_t)rowG * 2 + 1] = L;
                }
            } else {
                const float inv = 1.f / L;
                float* op = out + (size_t)(i0 + rowL) * RS + boff;
#pragma unroll
                for (int dt = 0; dt < 4; ++dt) {
                    const f32x4 o = (acc[isub][dt] * w0
                                  + (*(const f32x4*)&scrO[rowL * 68 + dt * 16 + q4 * 4]) * w1) * inv;
                    *(f32x4*)&op[dt * 16 + q4 * 4] = o;
                }
            }
        }
    }
}

extern "C" void kernel_launch(void* const* d_in, const int* in_sizes, int n_in,
                              void* d_out, int out_size, void* d_ws, size_t ws_size,
                              hipStream_t stream) {
    const float* q   = (const float*)d_in[0];
    const float* kh  = (const float*)d_in[1];
    const float* v   = (const float*)d_in[2];
    const float* kr  = (const float*)d_in[3];
    const float* se  = (const float*)d_in[4];
    const float* sm  = (const float*)d_in[5];
    const float* rwb = (const float*)d_in[6];
    const float* rrb = (const float*)d_in[7];
    const float* rsb = (const float*)d_in[8];
    const float* msk = (const float*)d_in[9];
    float* out = (float*)d_out;

    char* wsb = (char*)d_ws;
    u16x4* segP = (u16x4*)wsb;
    unsigned short* Kp  = (unsigned short*)(wsb + SEGP_BYTES);
    unsigned short* Krp = (unsigned short*)(wsb + SEGP_BYTES + KT_BYTES);
    unsigned short* Vtp = (unsigned short*)(wsb + SEGP_BYTES + 2 * KT_BYTES);
    float* opart  = (float*)(wsb + SEGP_BYTES + 3 * KT_BYTES);
    float* mlpart = (float*)(wsb + SEGP_BYTES + 3 * KT_BYTES + OPART_BYTES);

    const int jsplit = (ws_size >= (size_t)SEGP_BYTES + 3 * KT_BYTES + OPART_BYTES + ML_BYTES) ? 1 : 0;
    const int njt    = jsplit ? NJT_FULL / 2 : NJT_FULL;

    pack_seg_kernel<<<BSZ * QLEN * KLEN / 8 / 256, 256, 0, stream>>>(sm, msk, segP);
    pack_kv_kernel<<<NBN * NJT_FULL, 256, 0, stream>>>(kh, kr, v, Kp, Krp, Vtp);
    dim3 grid(QLEN / BLK_I, jsplit ? 2 : 1, NBN);
    relattn_kernel<<<grid, 256, 0, stream>>>(q, se, rwb, rrb, rsb, segP, Kp, Krp, Vtp,
                                             opart, mlpart, out, jsplit, njt);
    if (jsplit)
        merge_kernel<<<NBN * QLEN * DHEAD / 256, 256, 0, stream>>>(opart, mlpart, out);
}

// Round 11
// 68.837 us; speedup vs baseline: 1.2346x; 1.2346x over previous
//
#include <hip/hip_runtime.h>

#define QLEN 1024
#define KLEN 1024
#define BSZ 2
#define NHEAD 16
#define DHEAD 64
#define RS 2048            /* BSZ*NHEAD*DHEAD floats per seq row */
#define BLK_I 64
#define BLK_J 64
#define NJT_FULL (KLEN / BLK_J)
#define NBN (BSZ * NHEAD)

#define SC2f  0.18033688011112440f   /* 0.125 * log2(e) */
#define MBIGf 1.4426950408889634e30f /* 1e30 * log2(e)  */

#define SEGP_BYTES  16777216u                       /* BSZ*QLEN*KLEN*8  */
#define KT_BYTES    ((size_t)NBN * NJT_FULL * 8192) /* 4 MiB per tensor */

typedef __attribute__((ext_vector_type(8))) short s16x8;
typedef __attribute__((ext_vector_type(8))) unsigned short u16x8;
typedef __attribute__((ext_vector_type(4))) unsigned short u16x4;
typedef __attribute__((ext_vector_type(4))) float f32x4;
typedef __attribute__((ext_vector_type(2))) float f32x2;

__device__ __forceinline__ unsigned short f2bf(float f) {
    union { float f; unsigned int u; } x; x.f = f;
    unsigned int r = x.u + 0x7fffu + ((x.u >> 16) & 1u);
    return (unsigned short)(r >> 16);
}
__device__ __forceinline__ float bf2f(unsigned short h) {
    union { unsigned int u; float f; } x; x.u = ((unsigned int)h) << 16;
    return x.f;
}

typedef const __attribute__((address_space(1))) unsigned int* gas_t;
typedef __attribute__((address_space(3))) unsigned int* las_t;
__device__ __forceinline__ void gl_lds16(const void* g, void* l) {
    __builtin_amdgcn_global_load_lds((gas_t)g, (las_t)l, 16, 0, 0);
}

// ---- fused pre-pass (bodies verbatim from the round-8 PASSING kernels) ------
// blocks [0, 1024):      pack segmat+mask -> segP[b][i][j] {s0,s1,mk*MBIG,0} bf16
// blocks [1024, 1536):   pack Kh, Kr(+1), V^T as flat 8KB bf16 tiles, bank-swizzled
__global__ __launch_bounds__(256)
void pack_all_kernel(const float* __restrict__ segmat,
                     const float* __restrict__ mask,
                     const float* __restrict__ kh,
                     const float* __restrict__ kr,
                     const float* __restrict__ v,
                     u16x4* __restrict__ segP,
                     unsigned short* __restrict__ Kp,
                     unsigned short* __restrict__ Krp,
                     unsigned short* __restrict__ Vtp)
{
    __shared__ float VT[64][65];
    const int bid = blockIdx.x;
    const int tid = threadIdx.x;

    if (bid < 1024) {
        const int gid = bid * 256 + tid;          // BSZ*QLEN*KLEN/8 items
        const int j8  = gid & (KLEN / 8 - 1);
        const int i   = (gid >> 7) & (QLEN - 1);
        const int b   = gid >> 17;
        const float* sp = segmat + ((size_t)(i * KLEN + j8 * 8) * BSZ + b) * 2;
        const float* mp = mask + (size_t)i * KLEN + j8 * 8;
        u16x4* op = segP + (size_t)(b * QLEN + i) * KLEN + j8 * 8;
#pragma unroll
        for (int e = 0; e < 8; ++e) {
            const f32x2 sm = *(const f32x2*)(sp + e * (BSZ * 2));
            u16x4 pk;
            pk[0] = f2bf(sm[0]); pk[1] = f2bf(sm[1]);
            pk[2] = f2bf(mp[e] * MBIGf); pk[3] = 0;
            op[e] = pk;
        }
    } else {
        const int blk = bid - 1024;               // bn*NJT_FULL + jt
        const int bn  = blk >> 4;
        const int jt  = blk & (NJT_FULL - 1);
        const int b   = bn & 1;
        const int n   = bn >> 1;
        const int boff = b * NHEAD * DHEAD + n * DHEAD;
        const int j0  = jt * BLK_J;

        {   // v tile -> LDS (coalesced)
            const int j  = tid >> 2;
            const int dq = (tid & 3) * 16;
            const float* vp = v + (size_t)(j0 + j) * RS + boff + dq;
#pragma unroll
            for (int e = 0; e < 16; ++e) VT[j][dq + e] = vp[e];
        }
        __syncthreads();

        const size_t tb = (size_t)blk * 4096;     // u16 units (8KB tiles)
#pragma unroll
        for (int h = 0; h < 2; ++h) {
            const int p   = tid + h * 256;        // 16B chunk id 0..511
            const int row = p >> 3;
            const int ch  = (p & 7) ^ (row & 7);  // bank swizzle
            u16x8 ok, orr, ov;
            const float* hp = kh + (size_t)(j0 + row) * RS + boff + ch * 8;
            const float* rp = kr + (size_t)(j0 + row + 1) * RS + boff + ch * 8; // shift +1
#pragma unroll
            for (int e = 0; e < 8; ++e) {
                ok[e]  = f2bf(hp[e]);
                orr[e] = f2bf(rp[e]);
                ov[e]  = f2bf(VT[ch * 8 + e][row]);
            }
            *(u16x8*)&Kp [tb + (size_t)p * 8] = ok;
            *(u16x8*)&Krp[tb + (size_t)p * 8] = orr;
            *(u16x8*)&Vtp[tb + (size_t)p * 8] = ov;
        }
    }
}

// ---- main: swapped-QK (S^T in regs, lane-local rows), PlP P-exchange --------
// (verbatim round-8 structure; jsplit disabled at launch)
__global__ __launch_bounds__(256, 3)
void relattn_kernel(const float* __restrict__ q,
                    const float* __restrict__ segemb,
                    const float* __restrict__ rwb,
                    const float* __restrict__ rrb,
                    const float* __restrict__ rsb,
                    const u16x4* __restrict__ segP,
                    const unsigned short* __restrict__ Kp,
                    const unsigned short* __restrict__ Krp,
                    const unsigned short* __restrict__ Vtp,
                    float* __restrict__ out,
                    int njt)
{
    __shared__ unsigned short KhL[2][64][64];
    __shared__ unsigned short KrL[2][64][64];
    __shared__ unsigned short VtL[2][64][64];
    __shared__ unsigned short PlP[4][16][40];   // per-wave P^T xchg buffer (5KB)

    const int i0  = blockIdx.x * BLK_I;
    const int bn  = blockIdx.z;
    const int b   = bn & 1;
    const int n   = bn >> 1;
    const int boff = b * NHEAD * DHEAD + n * DHEAD;

    const int tid  = threadIdx.x;
    const int wave = tid >> 6;
    const int lane = tid & 63;
    const int q4   = lane >> 4;
    const int c    = lane & 15;
    const int ih   = wave >> 1;   // i-half: rows ih*32..+32
    const int jh   = wave & 1;    // j-half: cols jh*32..+32

    // ---- Q fragments + in-lane ef0 (no LDS) ----
    s16x8 qwf[2][2], qrf[2][2];
    float e0[2], e1[2];
#pragma unroll
    for (int isub = 0; isub < 2; ++isub) {
        const float* qp = q + (size_t)(i0 + ih * 32 + isub * 16 + c) * RS + boff;
        float es0 = 0.f, es1 = 0.f;
#pragma unroll
        for (int kk = 0; kk < 2; ++kk) {
            const int off = kk * 32 + q4 * 8;
            const f32x4 q0 = *(const f32x4*)(qp + off);
            const f32x4 q1 = *(const f32x4*)(qp + off + 4);
            const f32x4 w0 = *(const f32x4*)(rwb + n * DHEAD + off);
            const f32x4 w1 = *(const f32x4*)(rwb + n * DHEAD + off + 4);
            const f32x4 r0 = *(const f32x4*)(rrb + n * DHEAD + off);
            const f32x4 r1 = *(const f32x4*)(rrb + n * DHEAD + off + 4);
            const f32x4 sa = *(const f32x4*)(segemb + n * DHEAD + off);
            const f32x4 sb = *(const f32x4*)(segemb + n * DHEAD + off + 4);
            const f32x4 ta = *(const f32x4*)(segemb + (NHEAD + n) * DHEAD + off);
            const f32x4 tb = *(const f32x4*)(segemb + (NHEAD + n) * DHEAD + off + 4);
            const f32x4 ra = *(const f32x4*)(rsb + n * DHEAD + off);
            const f32x4 rb = *(const f32x4*)(rsb + n * DHEAD + off + 4);
            s16x8 tw, tr;
#pragma unroll
            for (int e = 0; e < 4; ++e) {
                tw[e]     = (short)f2bf(q0[e] + w0[e]);
                tw[4 + e] = (short)f2bf(q1[e] + w1[e]);
                tr[e]     = (short)f2bf(q0[e] + r0[e]);
                tr[4 + e] = (short)f2bf(q1[e] + r1[e]);
                es0 += (q0[e] + ra[e]) * sa[e] + (q1[e] + rb[e]) * sb[e];
                es1 += (q0[e] + ra[e]) * ta[e] + (q1[e] + rb[e]) * tb[e];
            }
            qwf[isub][kk] = tw; qrf[isub][kk] = tr;
        }
        es0 += __shfl_xor(es0, 16, 64); es0 += __shfl_xor(es0, 32, 64);
        es1 += __shfl_xor(es1, 16, 64); es1 += __shfl_xor(es1, 32, 64);
        e0[isub] = es0 * SC2f; e1[isub] = es1 * SC2f;
    }

    // ---- async DMA staging ----
    const int tbase = bn * NJT_FULL;
    auto stage = [&](int jt, int buf) {
        const size_t toff = ((size_t)(tbase + jt)) << 13;
        const int go = wave * 1024 + lane * 16;
        const int lo = wave * 1024;
#pragma unroll
        for (int h = 0; h < 2; ++h) {
            gl_lds16((const char*)Kp  + toff + go + h * 4096, (char*)&KhL[buf][0][0] + lo + h * 4096);
            gl_lds16((const char*)Krp + toff + go + h * 4096, (char*)&KrL[buf][0][0] + lo + h * 4096);
            gl_lds16((const char*)Vtp + toff + go + h * 4096, (char*)&VtL[buf][0][0] + lo + h * 4096);
        }
    };

    stage(0, 0);
    __syncthreads();

    float mreg[2] = { -INFINITY, -INFINITY };
    float lsum[2] = { 0.f, 0.f };
    f32x4 acc[2][4];
#pragma unroll
    for (int isub = 0; isub < 2; ++isub)
#pragma unroll
        for (int dt = 0; dt < 4; ++dt) acc[isub][dt] = (f32x4)0.f;

    const u16x4* spB = segP + (size_t)b * QLEN * KLEN;
    int cur = 0;
    for (int jt = 0; jt < njt; ++jt) {
        if (jt + 1 < njt) stage(jt + 1, cur ^ 1);   // DMA flies under compute

        // ---- seg/mask gathers: lane-local rows (i=c), 2x16B per (isub,js) ----
        const int jb = jt * BLK_J + jh * 32;
        u16x8 pg[2][2][2];
#pragma unroll
        for (int isub = 0; isub < 2; ++isub)
#pragma unroll
            for (int js = 0; js < 2; ++js) {
                const u16x4* pp = spB + (size_t)(i0 + ih * 32 + isub * 16 + c) * KLEN
                                  + jb + js * 16 + q4 * 4;
                pg[isub][js][0] = *(const u16x8*)pp;
                pg[isub][js][1] = *(const u16x8*)(pp + 2);
            }

        // ---- S^T = (Kh Qw^T + Kr Qr^T): D[j][i], lane holds row i=c ----
        f32x4 sjT[2][2];
#pragma unroll
        for (int isub = 0; isub < 2; ++isub) { sjT[isub][0] = (f32x4)0.f; sjT[isub][1] = (f32x4)0.f; }
        __builtin_amdgcn_s_setprio(1);
#pragma unroll
        for (int kk = 0; kk < 2; ++kk)
#pragma unroll
            for (int js = 0; js < 2; ++js) {
                const int row = jh * 32 + js * 16 + c;
                const int pcK = ((kk * 4 + q4) ^ (c & 7)) * 8;
                const s16x8 khf = *(const s16x8*)&KhL[cur][row][pcK];
                const s16x8 krf = *(const s16x8*)&KrL[cur][row][pcK];
#pragma unroll
                for (int isub = 0; isub < 2; ++isub) {
                    sjT[isub][js] = __builtin_amdgcn_mfma_f32_16x16x32_bf16(khf, qwf[isub][kk], sjT[isub][js], 0, 0, 0);
                    sjT[isub][js] = __builtin_amdgcn_mfma_f32_16x16x32_bf16(krf, qrf[isub][kk], sjT[isub][js], 0, 0, 0);
                }
            }
        __builtin_amdgcn_s_setprio(0);

        // ---- bias + lane-local online softmax + PV, per isub ----
#pragma unroll
        for (int isub = 0; isub < 2; ++isub) {
            float p[8];
#pragma unroll
            for (int js = 0; js < 2; ++js)
#pragma unroll
                for (int r = 0; r < 4; ++r) {
                    const u16x8 g = pg[isub][js][r >> 1];
                    const int bb = (r & 1) * 4;
                    const float bias = bf2f(g[bb]) * e0[isub] + bf2f(g[bb + 1]) * e1[isub]
                                       - bf2f(g[bb + 2]);
                    sjT[isub][js][r] = sjT[isub][js][r] * SC2f + bias;
                }
            float mt = fmaxf(
                fmaxf(fmaxf(sjT[isub][0][0], sjT[isub][0][1]), fmaxf(sjT[isub][0][2], sjT[isub][0][3])),
                fmaxf(fmaxf(sjT[isub][1][0], sjT[isub][1][1]), fmaxf(sjT[isub][1][2], sjT[isub][1][3])));
            mt = fmaxf(mt, __shfl_xor(mt, 16, 64));
            mt = fmaxf(mt, __shfl_xor(mt, 32, 64));
            const float mn  = fmaxf(mreg[isub], mt);
            const float scl = __builtin_amdgcn_exp2f(mreg[isub] - mn);
            mreg[isub] = mn;
#pragma unroll
            for (int dt = 0; dt < 4; ++dt) acc[isub][dt] *= scl;
            float ps = 0.f;
#pragma unroll
            for (int js = 0; js < 2; ++js)
#pragma unroll
                for (int r = 0; r < 4; ++r) {
                    const float pv = __builtin_amdgcn_exp2f(sjT[isub][js][r] - mn);
                    p[js * 4 + r] = pv;
                    ps += pv;
                }
            lsum[isub] = lsum[isub] * scl + ps;

            // pack P^T -> PlP (q4-crosslane redistribution via LDS)
#pragma unroll
            for (int js = 0; js < 2; ++js) {
                unsigned int wlo, whi;
                asm("v_cvt_pk_bf16_f32 %0, %1, %2" : "=v"(wlo) : "v"(p[js * 4 + 0]), "v"(p[js * 4 + 1]));
                asm("v_cvt_pk_bf16_f32 %0, %1, %2" : "=v"(whi) : "v"(p[js * 4 + 2]), "v"(p[js * 4 + 3]));
                uint2 wv; wv.x = wlo; wv.y = whi;
                *(uint2*)((char*)&PlP[wave][c][0] + js * 32 + q4 * 8) = wv;
            }
            const s16x8 pf = *(const s16x8*)&PlP[wave][c][q4 * 8];

            // PV: acc^T[d][i] += V^T(16d x 32j) * P^T(32j x 16i)
            __builtin_amdgcn_s_setprio(1);
#pragma unroll
            for (int dt = 0; dt < 4; ++dt) {
                const s16x8 vf = *(const s16x8*)&VtL[cur][dt * 16 + c]
                                   [((jh * 4 + q4) ^ (c & 7)) * 8];
                acc[isub][dt] = __builtin_amdgcn_mfma_f32_16x16x32_bf16(vf, pf, acc[isub][dt], 0, 0, 0);
            }
            __builtin_amdgcn_s_setprio(0);
        }

        __syncthreads();   // drains DMA + all waves done with buf[cur]
        cur ^= 1;
    }

    // ---- full-row lsum (reduce over q4 groups) ----
#pragma unroll
    for (int isub = 0; isub < 2; ++isub) {
        lsum[isub] += __shfl_xor(lsum[isub], 16, 64);
        lsum[isub] += __shfl_xor(lsum[isub], 32, 64);
    }

    // ---- jh merge via LDS, then store ----
    __syncthreads();
    float* scrO  = (float*)&KhL[0][0][0];   // [64][68] f32 over Kh+Kr (17.4KB)
    float* scrML = (float*)&VtL[0][0][0];   // [64][2]
    if (jh == 1) {
#pragma unroll
        for (int isub = 0; isub < 2; ++isub) {
            const int rowL = ih * 32 + isub * 16 + c;
#pragma unroll
            for (int dt = 0; dt < 4; ++dt)
                *(f32x4*)&scrO[rowL * 68 + dt * 16 + q4 * 4] = acc[isub][dt];
            if (q4 == 0) {
                scrML[rowL * 2]     = mreg[isub];
                scrML[rowL * 2 + 1] = lsum[isub];
            }
        }
    }
    __syncthreads();
    if (jh == 0) {
#pragma unroll
        for (int isub = 0; isub < 2; ++isub) {
            const int rowL = ih * 32 + isub * 16 + c;
            const float m1 = scrML[rowL * 2];
            const float l1 = scrML[rowL * 2 + 1];
            const float M  = fmaxf(mreg[isub], m1);
            const float w0 = __builtin_amdgcn_exp2f(mreg[isub] - M);
            const float w1 = __builtin_amdgcn_exp2f(m1 - M);
            const float L  = lsum[isub] * w0 + l1 * w1;
            const float inv = 1.f / L;
            float* op = out + (size_t)(i0 + rowL) * RS + boff;
#pragma unroll
            for (int dt = 0; dt < 4; ++dt) {
                const f32x4 o = (acc[isub][dt] * w0
                              + (*(const f32x4*)&scrO[rowL * 68 + dt * 16 + q4 * 4]) * w1) * inv;
                *(f32x4*)&op[dt * 16 + q4 * 4] = o;
            }
        }
    }
}

extern "C" void kernel_launch(void* const* d_in, const int* in_sizes, int n_in,
                              void* d_out, int out_size, void* d_ws, size_t ws_size,
                              hipStream_t stream) {
    const float* q   = (const float*)d_in[0];
    const float* kh  = (const float*)d_in[1];
    const float* v   = (const float*)d_in[2];
    const float* kr  = (const float*)d_in[3];
    const float* se  = (const float*)d_in[4];
    const float* sm  = (const float*)d_in[5];
    const float* rwb = (const float*)d_in[6];
    const float* rrb = (const float*)d_in[7];
    const float* rsb = (const float*)d_in[8];
    const float* msk = (const float*)d_in[9];
    float* out = (float*)d_out;

    char* wsb = (char*)d_ws;   // needs 16.8 + 12.6 = 29.4 MB (ws >= 46.7 MB proven in r8)
    u16x4* segP = (u16x4*)wsb;
    unsigned short* Kp  = (unsigned short*)(wsb + SEGP_BYTES);
    unsigned short* Krp = (unsigned short*)(wsb + SEGP_BYTES + KT_BYTES);
    unsigned short* Vtp = (unsigned short*)(wsb + SEGP_BYTES + 2 * KT_BYTES);

    pack_all_kernel<<<1024 + NBN * NJT_FULL, 256, 0, stream>>>(sm, msk, kh, kr, v,
                                                               segP, Kp, Krp, Vtp);
    dim3 grid(QLEN / BLK_I, 1, NBN);
    relattn_kernel<<<grid, 256, 0, stream>>>(q, se, rwb, rrb, rsb, segP, Kp, Krp, Vtp,
                                             out, NJT_FULL);
}